// Round 2
// baseline (1053.704 us; speedup 1.0000x reference)
//
#include <hip/hip_runtime.h>

#define N_NODES 100000
#define N_EDGES 1600000
#define N_TOT   1700000   // edges + self-loops
#define D_IN    128
#define D_H     8
#define N_MASK  10000

__device__ __forceinline__ float lrelu(float v, float s){ return v > 0.f ? v : s*v; }

__device__ __forceinline__ float wave_sum(float v){
#pragma unroll
  for (int o = 32; o > 0; o >>= 1) v += __shfl_xor(v, o, 64);
  return v;
}

// mask_slot[node] = slot index (0..N_MASK-1) or -1
__global__ void k_mask_slot(const int* __restrict__ mask_nodes, int* __restrict__ mask_slot){
  int i = blockIdx.x*blockDim.x + threadIdx.x;
  if (i < N_MASK) mask_slot[mask_nodes[i]] = i;
}

// v[0..7] = dec_W^T a_src, v[8..15] = dec_W^T a_dst   (dec_W is [128][8] row-major = W.T layout)
__global__ void k_dec_vec(const float* __restrict__ Wd, const float* __restrict__ a_src,
                          const float* __restrict__ a_dst, float* __restrict__ v){
  int k = threadIdx.x;
  if (k < 16){
    const float* a = (k < 8) ? a_src : a_dst;
    int kk = k & 7;
    float s = 0.f;
    for (int j = 0; j < D_IN; ++j) s += a[j] * Wd[j*D_H + kk];
    v[k] = s;
  }
}

// encoder node stage: h1 = use_x @ W^T, as1/ad1 = h1·a_src / h1·a_dst (wave per node)
__global__ void k_enc_node(const float* __restrict__ x, const float* __restrict__ token,
                           const float* __restrict__ W, const float* __restrict__ a_src,
                           const float* __restrict__ a_dst, const int* __restrict__ mask_slot,
                           float* __restrict__ h1, float* __restrict__ as1, float* __restrict__ ad1){
  __shared__ float Ws[D_H*D_IN];
  for (int t = threadIdx.x; t < D_H*D_IN; t += blockDim.x) Ws[t] = W[t];
  __syncthreads();
  int wid  = (blockIdx.x*blockDim.x + threadIdx.x) >> 6;
  int lane = threadIdx.x & 63;
  if (wid >= N_NODES) return;
  const float* row = (mask_slot[wid] >= 0) ? token : (x + (size_t)wid*D_IN);
  float2 xv = *(const float2*)(row + 2*lane);
  float p[D_H];
#pragma unroll
  for (int j = 0; j < D_H; ++j)
    p[j] = xv.x*Ws[j*D_IN + 2*lane] + xv.y*Ws[j*D_IN + 2*lane + 1];
#pragma unroll
  for (int j = 0; j < D_H; ++j) p[j] = wave_sum(p[j]);
  if (lane == 0){
    float as = 0.f, ad = 0.f;
#pragma unroll
    for (int j = 0; j < D_H; ++j){
      h1[(size_t)wid*D_H + j] = p[j];
      as += p[j]*a_src[j];
      ad += p[j]*a_dst[j];
    }
    as1[wid] = as; ad1[wid] = ad;
  }
}

// fused encoder edge pass: denom1[d] += ex ; acc1[d][:] += ex * h1[s][:]   (unnormalized)
__global__ void k_enc_edge(const int* __restrict__ ei, const float* __restrict__ as1,
                           const float* __restrict__ ad1, const float* __restrict__ h1,
                           float* __restrict__ denom1, float* __restrict__ acc1){
  int t = blockIdx.x*blockDim.x + threadIdx.x;
  if (t >= N_TOT) return;
  int s, d;
  if (t < N_EDGES){ s = ei[t]; d = ei[N_EDGES + t]; } else { s = t - N_EDGES; d = s; }
  float ex = __expf(lrelu(as1[s] + ad1[d], 0.2f));
  atomicAdd(&denom1[d], ex);
  float4 ha = *(const float4*)(h1 + (size_t)s*D_H);
  float4 hb = *(const float4*)(h1 + (size_t)s*D_H + 4);
  float* a = acc1 + (size_t)d*D_H;
  atomicAdd(a+0, ex*ha.x); atomicAdd(a+1, ex*ha.y);
  atomicAdd(a+2, ex*ha.z); atomicAdd(a+3, ex*ha.w);
  atomicAdd(a+4, ex*hb.x); atomicAdd(a+5, ex*hb.y);
  atomicAdd(a+6, ex*hb.z); atomicAdd(a+7, ex*hb.w);
}

// encoder finish: enc_rep = lrelu(acc1/denom1 + b, .01) -> d_out; rep = enc_rep @ e2d_W^T (masked->0)
// also as2/ad2 = rep · v_src / v_dst  (decoder attention logits, rep-space)
__global__ void k_enc_fin(const float* __restrict__ acc1, const float* __restrict__ denom1,
                          const float* __restrict__ enc_b, const float* __restrict__ e2dW,
                          const int* __restrict__ mask_slot, const float* __restrict__ v,
                          float* __restrict__ out_rep, float* __restrict__ rep,
                          float* __restrict__ as2, float* __restrict__ ad2){
  int i = blockIdx.x*blockDim.x + threadIdx.x;
  if (i >= N_NODES) return;
  float inv = 1.0f / denom1[i];     // self-loop guarantees denom1 > 0
  float er[D_H];
#pragma unroll
  for (int j = 0; j < D_H; ++j){
    er[j] = lrelu(acc1[(size_t)i*D_H + j]*inv + enc_b[j], 0.01f);
    out_rep[(size_t)i*D_H + j] = er[j];
  }
  bool masked = mask_slot[i] >= 0;
  float as = 0.f, ad = 0.f;
#pragma unroll
  for (int k = 0; k < D_H; ++k){
    float rv = 0.f;
#pragma unroll
    for (int j = 0; j < D_H; ++j) rv += er[j]*e2dW[k*D_H + j];
    rv = masked ? 0.f : rv;
    rep[(size_t)i*D_H + k] = rv;
    as += rv * v[k];
    ad += rv * v[8 + k];
  }
  as2[i] = as; ad2[i] = ad;
}

// fused decoder edge pass (rep-space, masked dst only):
// denom2[slot] += ex ; agg2[slot][:] += ex * rep[s][:]
__global__ void k_dec_edge(const int* __restrict__ ei, const int* __restrict__ mask_slot,
                           const float* __restrict__ as2, const float* __restrict__ ad2,
                           const float* __restrict__ rep, float* __restrict__ denom2,
                           float* __restrict__ agg2){
  int t = blockIdx.x*blockDim.x + threadIdx.x;
  if (t >= N_TOT) return;
  int s, d;
  if (t < N_EDGES){ s = ei[t]; d = ei[N_EDGES + t]; } else { s = t - N_EDGES; d = s; }
  int slot = mask_slot[d];
  if (slot < 0) return;
  float ex = __expf(lrelu(as2[s] + ad2[d], 0.2f));
  atomicAdd(&denom2[slot], ex);
  float4 r0 = *(const float4*)(rep + (size_t)s*D_H);
  float4 r1 = *(const float4*)(rep + (size_t)s*D_H + 4);
  float* a = agg2 + (size_t)slot*D_H;
  atomicAdd(a+0, ex*r0.x); atomicAdd(a+1, ex*r0.y);
  atomicAdd(a+2, ex*r0.z); atomicAdd(a+3, ex*r0.w);
  atomicAdd(a+4, ex*r1.x); atomicAdd(a+5, ex*r1.y);
  atomicAdd(a+6, ex*r1.z); atomicAdd(a+7, ex*r1.w);
}

// loss: wave per masked slot; recon = lrelu((agg2/denom2) @ Wd^T + dec_b, .01); cosine vs x
__global__ void k_loss(const float* __restrict__ agg2, const float* __restrict__ denom2,
                       const float* __restrict__ Wd, const float* __restrict__ dec_b,
                       const int* __restrict__ mask_nodes, const float* __restrict__ x,
                       float* __restrict__ cos_sum){
  __shared__ float Ws[D_IN*D_H];
  for (int t = threadIdx.x; t < D_IN*D_H; t += blockDim.x) Ws[t] = Wd[t];
  __syncthreads();
  int wid  = (blockIdx.x*blockDim.x + threadIdx.x) >> 6;
  int lane = threadIdx.x & 63;
  if (wid >= N_MASK) return;
  int node = mask_nodes[wid];
  float inv = 1.0f / denom2[wid];   // masked node's self-loop guarantees denom2 > 0
  float a[D_H];
#pragma unroll
  for (int k = 0; k < D_H; ++k) a[k] = agg2[(size_t)wid*D_H + k]*inv;
  float dot = 0.f, na = 0.f, nb = 0.f;
#pragma unroll
  for (int h = 0; h < 2; ++h){
    int f = lane + 64*h;
    float r = dec_b[f];
#pragma unroll
    for (int k = 0; k < D_H; ++k) r += a[k]*Ws[f*D_H + k];
    r = lrelu(r, 0.01f);
    float xi = x[(size_t)node*D_IN + f];
    dot += r*xi; na += r*r; nb += xi*xi;
  }
  dot = wave_sum(dot); na = wave_sum(na); nb = wave_sum(nb);
  if (lane == 0){
    float den = fmaxf(sqrtf(na), 1e-8f) * fmaxf(sqrtf(nb), 1e-8f);
    atomicAdd(cos_sum, dot/den);
  }
}

__global__ void k_fin(const float* __restrict__ cos_sum, float* __restrict__ out){
  out[0] = 1.0f - cos_sum[0] / (float)N_MASK;
}

extern "C" void kernel_launch(void* const* d_in, const int* in_sizes, int n_in,
                              void* d_out, int out_size, void* d_ws, size_t ws_size,
                              hipStream_t stream){
  const float* x          = (const float*)d_in[0];
  const int*   ei         = (const int*)  d_in[1];
  const int*   mask_nodes = (const int*)  d_in[2];
  const float* token      = (const float*)d_in[3];
  const float* enc_W      = (const float*)d_in[4];
  const float* enc_as     = (const float*)d_in[5];
  const float* enc_ad     = (const float*)d_in[6];
  const float* enc_b      = (const float*)d_in[7];
  const float* e2d_W      = (const float*)d_in[8];
  const float* dec_W      = (const float*)d_in[9];
  const float* dec_as     = (const float*)d_in[10];
  const float* dec_ad     = (const float*)d_in[11];
  const float* dec_b      = (const float*)d_in[12];
  float* out = (float*)d_out;

  char* w = (char*)d_ws;
  size_t off = 0;
  auto alloc = [&](size_t bytes)->char*{ char* p = w + off; off += (bytes + 255)/256*256; return p; };
  // ---- zero-init region ----
  float* denom1  = (float*)alloc((size_t)N_NODES*4);
  float* acc1    = (float*)alloc((size_t)N_NODES*D_H*4);
  float* denom2  = (float*)alloc((size_t)N_MASK*4);
  float* agg2    = (float*)alloc((size_t)N_MASK*D_H*4);
  float* cos_sum = (float*)alloc(4);
  size_t zero_bytes = off;
  // ---- uninitialized scratch ----
  int*   mask_slot = (int*)  alloc((size_t)N_NODES*4);
  float* h1   = (float*)alloc((size_t)N_NODES*D_H*4);
  float* as1  = (float*)alloc((size_t)N_NODES*4);
  float* ad1  = (float*)alloc((size_t)N_NODES*4);
  float* rep  = (float*)alloc((size_t)N_NODES*D_H*4);
  float* as2  = (float*)alloc((size_t)N_NODES*4);
  float* ad2  = (float*)alloc((size_t)N_NODES*4);
  float* vvec = (float*)alloc(16*4);

  hipMemsetAsync(d_ws, 0, zero_bytes, stream);
  hipMemsetAsync(mask_slot, 0xFF, (size_t)N_NODES*4, stream);

  k_mask_slot<<<(N_MASK + 255)/256, 256, 0, stream>>>(mask_nodes, mask_slot);
  k_dec_vec  <<<1, 64, 0, stream>>>(dec_W, dec_as, dec_ad, vvec);
  k_enc_node <<<(N_NODES*64 + 255)/256, 256, 0, stream>>>(x, token, enc_W, enc_as, enc_ad,
                                                          mask_slot, h1, as1, ad1);
  k_enc_edge <<<(N_TOT + 255)/256, 256, 0, stream>>>(ei, as1, ad1, h1, denom1, acc1);
  k_enc_fin  <<<(N_NODES + 255)/256, 256, 0, stream>>>(acc1, denom1, enc_b, e2d_W, mask_slot,
                                                       vvec, out + 1, rep, as2, ad2);
  k_dec_edge <<<(N_TOT + 255)/256, 256, 0, stream>>>(ei, mask_slot, as2, ad2, rep, denom2, agg2);
  k_loss     <<<(N_MASK*64 + 255)/256, 256, 0, stream>>>(agg2, denom2, dec_W, dec_b,
                                                         mask_nodes, x, cos_sum);
  k_fin      <<<1, 1, 0, stream>>>(cos_sum, out);
}

// Round 3
// 276.556 us; speedup vs baseline: 3.8101x; 3.8101x over previous
//
#include <hip/hip_runtime.h>

#define N_NODES 100000
#define N_EDGES 1600000
#define N_TOT   1700000   // edges + self-loops
#define D_IN    128
#define D_H     8
#define N_MASK  10000

#define TS     1792      // dst-tile size; LDS acc = 1792*9*4 = 63 KB
#define NTE    56        // ceil(N_NODES/TS)
#define NTD    6         // ceil(N_MASK/TS)
#define CAPB   40960     // per-bucket capacity (mean ~30.5K, sigma ~180)
#define B_ENC  9         // blocks per enc tile  (grid 504 ~ 2/CU)
#define B_DEC  6         // blocks per dec tile

__device__ __forceinline__ float lrelu(float v, float s){ return v > 0.f ? v : s*v; }

__device__ __forceinline__ float wave_sum(float v){
#pragma unroll
  for (int o = 32; o > 0; o >>= 1) v += __shfl_xor(v, o, 64);
  return v;
}

__global__ void k_mask_slot(const int* __restrict__ mask_nodes, int* __restrict__ mask_slot){
  int i = blockIdx.x*blockDim.x + threadIdx.x;
  if (i < N_MASK) mask_slot[mask_nodes[i]] = i;
}

// v[0..7] = dec_W^T a_src  (dec_W row-major [128][8])
__global__ void k_dec_vec(const float* __restrict__ Wd, const float* __restrict__ a_src,
                          float* __restrict__ v){
  int k = threadIdx.x;
  if (k < D_H){
    float s = 0.f;
    for (int j = 0; j < D_IN; ++j) s += a_src[j] * Wd[j*D_H + k];
    v[k] = s;
  }
}

// h1 = use_x @ W^T, as1/ad1 = h1·a_src / h1·a_dst  (wave per node)
__global__ void k_enc_node(const float* __restrict__ x, const float* __restrict__ token,
                           const float* __restrict__ W, const float* __restrict__ a_src,
                           const float* __restrict__ a_dst, const int* __restrict__ mask_slot,
                           float* __restrict__ h1, float* __restrict__ as1, float* __restrict__ ad1){
  __shared__ float Ws[D_H*D_IN];
  for (int t = threadIdx.x; t < D_H*D_IN; t += blockDim.x) Ws[t] = W[t];
  __syncthreads();
  int wid  = (blockIdx.x*blockDim.x + threadIdx.x) >> 6;
  int lane = threadIdx.x & 63;
  if (wid >= N_NODES) return;
  const float* row = (mask_slot[wid] >= 0) ? token : (x + (size_t)wid*D_IN);
  float2 xv = *(const float2*)(row + 2*lane);
  float p[D_H];
#pragma unroll
  for (int j = 0; j < D_H; ++j)
    p[j] = xv.x*Ws[j*D_IN + 2*lane] + xv.y*Ws[j*D_IN + 2*lane + 1];
#pragma unroll
  for (int j = 0; j < D_H; ++j) p[j] = wave_sum(p[j]);
  if (lane == 0){
    float as = 0.f, ad = 0.f;
#pragma unroll
    for (int j = 0; j < D_H; ++j){
      h1[(size_t)wid*D_H + j] = p[j];
      as += p[j]*a_src[j];
      ad += p[j]*a_dst[j];
    }
    as1[wid] = as; ad1[wid] = ad;
  }
}

// bucket edges by dst tile (enc) and by slot tile (dec, masked dst only)
// packed word: (src << 11) | local_index   (src < 2^17, local < 1792 < 2^11)
__global__ void k_bucket(const int* __restrict__ ei, const int* __restrict__ mask_slot,
                         int* __restrict__ gcur_enc, int* __restrict__ gcur_dec,
                         unsigned* __restrict__ be, unsigned* __restrict__ bd){
  __shared__ int h_enc[NTE], h_dec[NTD], base_enc[NTE], base_dec[NTD];
  int tid = threadIdx.x;
  if (tid < NTE) h_enc[tid] = 0;
  if (tid < NTD) h_dec[tid] = 0;
  __syncthreads();
  int s[4], d[4], sl[4];
  int t0 = blockIdx.x*4096;
#pragma unroll
  for (int k = 0; k < 4; ++k){
    int t = t0 + tid + k*1024;
    s[k] = -1;
    if (t < N_TOT){
      if (t < N_EDGES){ s[k] = ei[t]; d[k] = ei[N_EDGES + t]; }
      else            { s[k] = t - N_EDGES; d[k] = s[k]; }
      sl[k] = mask_slot[d[k]];
      atomicAdd(&h_enc[d[k]/TS], 1);
      if (sl[k] >= 0) atomicAdd(&h_dec[sl[k]/TS], 1);
    }
  }
  __syncthreads();
  if (tid < NTE){ base_enc[tid] = atomicAdd(&gcur_enc[tid], h_enc[tid]); h_enc[tid] = 0; }
  if (tid < NTD){ base_dec[tid] = atomicAdd(&gcur_dec[tid], h_dec[tid]); h_dec[tid] = 0; }
  __syncthreads();
#pragma unroll
  for (int k = 0; k < 4; ++k){
    if (s[k] >= 0){
      int b = d[k]/TS, loc = d[k] - b*TS;
      int idx = base_enc[b] + atomicAdd(&h_enc[b], 1);
      if (idx < CAPB) be[(size_t)b*CAPB + idx] = ((unsigned)s[k] << 11) | (unsigned)loc;
      if (sl[k] >= 0){
        int bs = sl[k]/TS, locs = sl[k] - bs*TS;
        int i2 = base_dec[bs] + atomicAdd(&h_dec[bs], 1);
        if (i2 < CAPB) bd[(size_t)bs*CAPB + i2] = ((unsigned)s[k] << 11) | (unsigned)locs;
      }
    }
  }
}

// per-tile LDS aggregation (unnormalized): lacc[loc][0..7] += ex*h1[s], [8] += ex
__global__ void __launch_bounds__(512) k_agg_enc(const unsigned* __restrict__ be,
                          const int* __restrict__ gcur_enc,
                          const float* __restrict__ as1, const float* __restrict__ ad1,
                          const float* __restrict__ h1, float* __restrict__ partial1){
  __shared__ float lacc[TS*9];
  int tau = blockIdx.x / B_ENC, p = blockIdx.x % B_ENC;
  for (int r = threadIdx.x; r < TS*9; r += blockDim.x) lacc[r] = 0.f;
  __syncthreads();
  int n  = min(gcur_enc[tau], CAPB);
  int lo = (int)((long long)n*p/B_ENC), hi = (int)((long long)n*(p+1)/B_ENC);
  const unsigned* bb = be + (size_t)tau*CAPB;
  int dbase = tau*TS;
  for (int i = lo + threadIdx.x; i < hi; i += blockDim.x){
    unsigned e = bb[i];
    int s = e >> 11, loc = e & 2047;
    float ex = __expf(lrelu(as1[s] + ad1[dbase + loc], 0.2f));
    float4 ha = *(const float4*)(h1 + (size_t)s*D_H);
    float4 hb = *(const float4*)(h1 + (size_t)s*D_H + 4);
    float* a = lacc + loc*9;
    atomicAdd(a+0, ex*ha.x); atomicAdd(a+1, ex*ha.y);
    atomicAdd(a+2, ex*ha.z); atomicAdd(a+3, ex*ha.w);
    atomicAdd(a+4, ex*hb.x); atomicAdd(a+5, ex*hb.y);
    atomicAdd(a+6, ex*hb.z); atomicAdd(a+7, ex*hb.w);
    atomicAdd(a+8, ex);
  }
  __syncthreads();
  float* out = partial1 + (size_t)blockIdx.x*(TS*9);
  for (int r = threadIdx.x; r < TS*9; r += blockDim.x) out[r] = lacc[r];
}

// sum partials -> enc_rep -> d_out ; rep (masked->0) ; ex2 = exp(lrelu(rep·v))
__global__ void k_enc_fin(const float* __restrict__ partial1, const float* __restrict__ enc_b,
                          const float* __restrict__ e2dW, const int* __restrict__ mask_slot,
                          const float* __restrict__ v, float* __restrict__ out_rep,
                          float* __restrict__ rep, float* __restrict__ ex2){
  int i = blockIdx.x*blockDim.x + threadIdx.x;
  if (i >= N_NODES) return;
  int tau = i / TS, dloc = i - tau*TS;
  float sum[9];
#pragma unroll
  for (int j = 0; j < 9; ++j) sum[j] = 0.f;
  for (int p = 0; p < B_ENC; ++p){
    const float* pp = partial1 + ((size_t)(tau*B_ENC + p))*(TS*9) + dloc*9;
#pragma unroll
    for (int j = 0; j < 9; ++j) sum[j] += pp[j];
  }
  float inv = 1.0f / sum[8];
  float er[D_H];
#pragma unroll
  for (int j = 0; j < D_H; ++j){
    er[j] = lrelu(sum[j]*inv + enc_b[j], 0.01f);
    out_rep[(size_t)i*D_H + j] = er[j];
  }
  bool masked = mask_slot[i] >= 0;
  float as = 0.f;
#pragma unroll
  for (int k = 0; k < D_H; ++k){
    float rv = 0.f;
#pragma unroll
    for (int j = 0; j < D_H; ++j) rv += er[j]*e2dW[k*D_H + j];
    rv = masked ? 0.f : rv;
    rep[(size_t)i*D_H + k] = rv;
    as += rv * v[k];
  }
  ex2[i] = __expf(lrelu(as, 0.2f));   // alpha_dst[masked]=0, so weight depends only on src
}

// decoder tile aggregation in rep space (masked dst only)
__global__ void __launch_bounds__(512) k_agg_dec(const unsigned* __restrict__ bd,
                          const int* __restrict__ gcur_dec,
                          const float* __restrict__ ex2, const float* __restrict__ rep,
                          float* __restrict__ partial2){
  __shared__ float lacc[TS*9];
  int sg = blockIdx.x / B_DEC, p = blockIdx.x % B_DEC;
  for (int r = threadIdx.x; r < TS*9; r += blockDim.x) lacc[r] = 0.f;
  __syncthreads();
  int n  = min(gcur_dec[sg], CAPB);
  int lo = (int)((long long)n*p/B_DEC), hi = (int)((long long)n*(p+1)/B_DEC);
  const unsigned* bb = bd + (size_t)sg*CAPB;
  for (int i = lo + threadIdx.x; i < hi; i += blockDim.x){
    unsigned e = bb[i];
    int s = e >> 11, loc = e & 2047;
    float ex = ex2[s];
    float4 r0 = *(const float4*)(rep + (size_t)s*D_H);
    float4 r1 = *(const float4*)(rep + (size_t)s*D_H + 4);
    float* a = lacc + loc*9;
    atomicAdd(a+0, ex*r0.x); atomicAdd(a+1, ex*r0.y);
    atomicAdd(a+2, ex*r0.z); atomicAdd(a+3, ex*r0.w);
    atomicAdd(a+4, ex*r1.x); atomicAdd(a+5, ex*r1.y);
    atomicAdd(a+6, ex*r1.z); atomicAdd(a+7, ex*r1.w);
    atomicAdd(a+8, ex);
  }
  __syncthreads();
  float* out = partial2 + (size_t)blockIdx.x*(TS*9);
  for (int r = threadIdx.x; r < TS*9; r += blockDim.x) out[r] = lacc[r];
}

// loss: 640 waves, each handles slots strided; block-reduce then 1 atomic/block
__global__ void k_loss(const float* __restrict__ partial2, const float* __restrict__ Wd,
                       const float* __restrict__ dec_b, const int* __restrict__ mask_nodes,
                       const float* __restrict__ x, float* __restrict__ cos_sum){
  __shared__ float Ws[D_IN*D_H];
  __shared__ float wsum[4];
  for (int t = threadIdx.x; t < D_IN*D_H; t += blockDim.x) Ws[t] = Wd[t];
  __syncthreads();
  int wv = threadIdx.x >> 6, lane = threadIdx.x & 63;
  int gw = blockIdx.x*4 + wv;
  float acc = 0.f;
  for (int slot = gw; slot < N_MASK; slot += 640){
    int sg = slot / TS, sl = slot - sg*TS;
    float aj = 0.f;
    if (lane < 9){
      for (int p = 0; p < B_DEC; ++p)
        aj += partial2[((size_t)(sg*B_DEC + p))*(TS*9) + sl*9 + lane];
    }
    float a[9];
#pragma unroll
    for (int j = 0; j < 9; ++j) a[j] = __shfl(aj, j, 64);
    float inv = 1.0f / a[8];
    int node = mask_nodes[slot];
    float dot = 0.f, na = 0.f, nb = 0.f;
#pragma unroll
    for (int hh = 0; hh < 2; ++hh){
      int f = lane + 64*hh;
      float r = dec_b[f];
#pragma unroll
      for (int k = 0; k < D_H; ++k) r += a[k]*inv*Ws[f*D_H + k];
      r = lrelu(r, 0.01f);
      float xi = x[(size_t)node*D_IN + f];
      dot += r*xi; na += r*r; nb += xi*xi;
    }
    dot = wave_sum(dot); na = wave_sum(na); nb = wave_sum(nb);
    if (lane == 0) acc += dot / (fmaxf(sqrtf(na), 1e-8f)*fmaxf(sqrtf(nb), 1e-8f));
  }
  if (lane == 0) wsum[wv] = acc;
  __syncthreads();
  if (threadIdx.x == 0) atomicAdd(cos_sum, wsum[0]+wsum[1]+wsum[2]+wsum[3]);
}

__global__ void k_fin(const float* __restrict__ cos_sum, float* __restrict__ out){
  out[0] = 1.0f - cos_sum[0] / (float)N_MASK;
}

extern "C" void kernel_launch(void* const* d_in, const int* in_sizes, int n_in,
                              void* d_out, int out_size, void* d_ws, size_t ws_size,
                              hipStream_t stream){
  const float* x          = (const float*)d_in[0];
  const int*   ei         = (const int*)  d_in[1];
  const int*   mask_nodes = (const int*)  d_in[2];
  const float* token      = (const float*)d_in[3];
  const float* enc_W      = (const float*)d_in[4];
  const float* enc_as     = (const float*)d_in[5];
  const float* enc_ad     = (const float*)d_in[6];
  const float* enc_b      = (const float*)d_in[7];
  const float* e2d_W      = (const float*)d_in[8];
  const float* dec_W      = (const float*)d_in[9];
  const float* dec_as     = (const float*)d_in[10];
  const float* dec_b      = (const float*)d_in[12];
  float* out = (float*)d_out;

  char* w = (char*)d_ws;
  size_t off = 0;
  auto alloc = [&](size_t bytes)->char*{ char* p = w + off; off += (bytes + 255)/256*256; return p; };
  // ---- zero-init region (small) ----
  int*   gcur_enc = (int*)  alloc(NTE*4);
  int*   gcur_dec = (int*)  alloc(NTD*4);
  float* cos_sum  = (float*)alloc(4);
  size_t zero_bytes = off;
  // ---- rest ----
  int*      mask_slot = (int*)     alloc((size_t)N_NODES*4);
  unsigned* be        = (unsigned*)alloc((size_t)NTE*CAPB*4);
  unsigned* bd        = (unsigned*)alloc((size_t)NTD*CAPB*4);
  float*    h1        = (float*)   alloc((size_t)N_NODES*D_H*4);
  float*    as1       = (float*)   alloc((size_t)N_NODES*4);
  float*    ad1       = (float*)   alloc((size_t)N_NODES*4);
  float*    rep       = (float*)   alloc((size_t)N_NODES*D_H*4);
  float*    ex2       = (float*)   alloc((size_t)N_NODES*4);
  float*    partial1  = (float*)   alloc((size_t)NTE*B_ENC*TS*9*4);
  float*    partial2  = (float*)   alloc((size_t)NTD*B_DEC*TS*9*4);
  float*    vvec      = (float*)   alloc(64);

  hipMemsetAsync(d_ws, 0, zero_bytes, stream);
  hipMemsetAsync(mask_slot, 0xFF, (size_t)N_NODES*4, stream);

  k_mask_slot<<<(N_MASK + 255)/256, 256, 0, stream>>>(mask_nodes, mask_slot);
  k_dec_vec  <<<1, 64, 0, stream>>>(dec_W, dec_as, vvec);
  k_enc_node <<<(N_NODES*64 + 255)/256, 256, 0, stream>>>(x, token, enc_W, enc_as, enc_ad,
                                                          mask_slot, h1, as1, ad1);
  k_bucket   <<<(N_TOT + 4095)/4096, 1024, 0, stream>>>(ei, mask_slot, gcur_enc, gcur_dec, be, bd);
  k_agg_enc  <<<NTE*B_ENC, 512, 0, stream>>>(be, gcur_enc, as1, ad1, h1, partial1);
  k_enc_fin  <<<(N_NODES + 255)/256, 256, 0, stream>>>(partial1, enc_b, e2d_W, mask_slot,
                                                       vvec, out + 1, rep, ex2);
  k_agg_dec  <<<NTD*B_DEC, 512, 0, stream>>>(bd, gcur_dec, ex2, rep, partial2);
  k_loss     <<<160, 256, 0, stream>>>(partial2, dec_W, dec_b, mask_nodes, x, cos_sum);
  k_fin      <<<1, 1, 0, stream>>>(cos_sum, out);
}

// Round 5
// 261.610 us; speedup vs baseline: 4.0278x; 1.0571x over previous
//
#include <hip/hip_runtime.h>

#define N_NODES 100000
#define N_EDGES 1600000
#define N_TOT   1700000   // edges + self-loops
#define D_IN    128
#define D_H     8
#define N_MASK  10000

#define TS      896       // dst-tile size; lacc = 896*9*4 = 32256 B (+ lad 3584 B)
#define NTE     112       // ceil(N_NODES/TS)
#define NTD     12        // ceil(N_MASK/TS)
#define CAPB    17408     // per-bucket capacity (mean ~15232, sigma ~123)
#define B_ENC   9         // blocks per enc tile  -> grid 1008 (~4/CU)
#define B_DEC   24        // blocks per dec tile  -> grid 288
#define NB_NODE 12500     // enc_node blocks in k_pre (8 nodes/block)
#define NB_BKT  831       // bucket blocks in k_pre (2048 edges/block)

__device__ __forceinline__ float lrelu(float v, float s){ return v > 0.f ? v : s*v; }

__device__ __forceinline__ float wave_sum(float v){
#pragma unroll
  for (int o = 32; o > 0; o >>= 1) v += __shfl_xor(v, o, 64);
  return v;
}

// mask_slot scatter + vvec (= dec_W^T dec_a_src) in block 0
__global__ void k_ms(const int* __restrict__ mask_nodes, int* __restrict__ mask_slot,
                     const float* __restrict__ Wd, const float* __restrict__ a_src,
                     float* __restrict__ vvec){
  int i = blockIdx.x*blockDim.x + threadIdx.x;
  if (i < N_MASK) mask_slot[mask_nodes[i]] = i;
  if (blockIdx.x == 0 && threadIdx.x < D_H){
    float s = 0.f;
    for (int j = 0; j < D_IN; ++j) s += a_src[j] * Wd[j*D_H + threadIdx.x];
    vvec[threadIdx.x] = s;
  }
}

// fused: blocks [0,NB_NODE) = encoder node stage (8 nodes/block, wave per node)
//        blocks [NB_NODE, NB_NODE+NB_BKT) = edge bucketing (2048 edges/block)
__global__ void __launch_bounds__(512) k_pre(
    const float* __restrict__ x, const float* __restrict__ token,
    const float* __restrict__ W, const float* __restrict__ a_src,
    const float* __restrict__ a_dst, const int* __restrict__ mask_slot,
    const int* __restrict__ ei,
    float* __restrict__ h1, float* __restrict__ as1, float* __restrict__ ad1,
    int* __restrict__ gcur_enc, int* __restrict__ gcur_dec,
    unsigned* __restrict__ be, unsigned* __restrict__ bd){
  __shared__ float smem[D_H*D_IN];   // enc: Ws ; bucket: histograms (aliased)
  if (blockIdx.x < NB_NODE){
    for (int t = threadIdx.x; t < D_H*D_IN; t += 512) smem[t] = W[t];
    __syncthreads();
    int wid  = blockIdx.x*8 + (threadIdx.x >> 6);     // < 100000 exactly
    int lane = threadIdx.x & 63;
    const float* row = (mask_slot[wid] >= 0) ? token : (x + (size_t)wid*D_IN);
    float2 xv = *(const float2*)(row + 2*lane);
    float p[D_H];
#pragma unroll
    for (int j = 0; j < D_H; ++j)
      p[j] = xv.x*smem[j*D_IN + 2*lane] + xv.y*smem[j*D_IN + 2*lane + 1];
#pragma unroll
    for (int j = 0; j < D_H; ++j) p[j] = wave_sum(p[j]);
    if (lane == 0){
      float as = 0.f, ad = 0.f;
#pragma unroll
      for (int j = 0; j < D_H; ++j){
        h1[(size_t)wid*D_H + j] = p[j];
        as += p[j]*a_src[j];
        ad += p[j]*a_dst[j];
      }
      as1[wid] = as; ad1[wid] = ad;
    }
  } else {
    int* h_enc    = (int*)smem;            // [NTE]
    int* base_enc = h_enc + NTE;           // [NTE]
    int* h_dec    = base_enc + NTE;        // [NTD]
    int* base_dec = h_dec + NTD;           // [NTD]
    int tid = threadIdx.x;
    if (tid < NTE){ h_enc[tid] = 0; }
    if (tid < NTD){ h_dec[tid] = 0; }
    __syncthreads();
    int t0 = (blockIdx.x - NB_NODE)*2048;
    int s[4], d[4], sl[4];
#pragma unroll
    for (int k = 0; k < 4; ++k){
      int t = t0 + tid + k*512;
      s[k] = -1;
      if (t < N_TOT){
        if (t < N_EDGES){ s[k] = ei[t]; d[k] = ei[N_EDGES + t]; }
        else            { s[k] = t - N_EDGES; d[k] = s[k]; }
        sl[k] = mask_slot[d[k]];
        atomicAdd(&h_enc[d[k]/TS], 1);
        if (sl[k] >= 0) atomicAdd(&h_dec[sl[k]/TS], 1);
      }
    }
    __syncthreads();
    if (tid < NTE){ base_enc[tid] = atomicAdd(&gcur_enc[tid], h_enc[tid]); h_enc[tid] = 0; }
    if (tid < NTD){ base_dec[tid] = atomicAdd(&gcur_dec[tid], h_dec[tid]); h_dec[tid] = 0; }
    __syncthreads();
#pragma unroll
    for (int k = 0; k < 4; ++k){
      if (s[k] >= 0){
        int b = d[k]/TS, loc = d[k] - b*TS;
        int idx = base_enc[b] + atomicAdd(&h_enc[b], 1);
        if (idx < CAPB) be[(size_t)b*CAPB + idx] = ((unsigned)s[k] << 10) | (unsigned)loc;
        if (sl[k] >= 0){
          int bs = sl[k]/TS, locs = sl[k] - bs*TS;
          int i2 = base_dec[bs] + atomicAdd(&h_dec[bs], 1);
          if (i2 < CAPB) bd[(size_t)bs*CAPB + i2] = ((unsigned)s[k] << 10) | (unsigned)locs;
        }
      }
    }
  }
}

// encoder tile aggregation, ILP-4: lacc[loc][0..7] += ex*h1[s], [8] += ex
__global__ void __launch_bounds__(512) k_agg_enc(const unsigned* __restrict__ be,
                          const int* __restrict__ gcur_enc,
                          const float* __restrict__ as1, const float* __restrict__ ad1,
                          const float* __restrict__ h1, float* __restrict__ partial1){
  __shared__ float lacc[TS*9];
  __shared__ float lad[TS];
  int tau = blockIdx.x / B_ENC, pb = blockIdx.x % B_ENC;
  for (int r = threadIdx.x; r < TS*9; r += 512) lacc[r] = 0.f;
  int gb = tau*TS;
  for (int r = threadIdx.x; r < TS; r += 512){
    int g = gb + r; lad[r] = (g < N_NODES) ? ad1[g] : 0.f;
  }
  __syncthreads();
  int n  = min(gcur_enc[tau], CAPB);
  int lo = (int)(((long long)n*pb/B_ENC) & ~3LL);
  int hi = (pb == B_ENC-1) ? n : (int)(((long long)n*(pb+1)/B_ENC) & ~3LL);
  const unsigned* bb = be + (size_t)tau*CAPB;
  auto acc9 = [&](int c, float ex, float4 ha, float4 hb){
    float* a = lacc + c*9;
    atomicAdd(a+0, ex*ha.x); atomicAdd(a+1, ex*ha.y);
    atomicAdd(a+2, ex*ha.z); atomicAdd(a+3, ex*ha.w);
    atomicAdd(a+4, ex*hb.x); atomicAdd(a+5, ex*hb.y);
    atomicAdd(a+6, ex*hb.z); atomicAdd(a+7, ex*hb.w);
    atomicAdd(a+8, ex);
  };
  for (int i = lo + 4*(int)threadIdx.x; i < hi; i += 4*512){
    if (i + 4 <= hi){
      uint4 e = *(const uint4*)(bb + i);
      int s0 = e.x>>10, c0 = e.x&1023, s1 = e.y>>10, c1 = e.y&1023;
      int s2 = e.z>>10, c2 = e.z&1023, s3 = e.w>>10, c3 = e.w&1023;
      float A0 = as1[s0], A1 = as1[s1], A2 = as1[s2], A3 = as1[s3];
      float4 h0a = *(const float4*)(h1 + (size_t)s0*D_H), h0b = *(const float4*)(h1 + (size_t)s0*D_H + 4);
      float4 h1a = *(const float4*)(h1 + (size_t)s1*D_H), h1b = *(const float4*)(h1 + (size_t)s1*D_H + 4);
      float4 h2a = *(const float4*)(h1 + (size_t)s2*D_H), h2b = *(const float4*)(h1 + (size_t)s2*D_H + 4);
      float4 h3a = *(const float4*)(h1 + (size_t)s3*D_H), h3b = *(const float4*)(h1 + (size_t)s3*D_H + 4);
      float e0 = __expf(lrelu(A0 + lad[c0], 0.2f));
      float e1 = __expf(lrelu(A1 + lad[c1], 0.2f));
      float e2 = __expf(lrelu(A2 + lad[c2], 0.2f));
      float e3 = __expf(lrelu(A3 + lad[c3], 0.2f));
      acc9(c0, e0, h0a, h0b); acc9(c1, e1, h1a, h1b);
      acc9(c2, e2, h2a, h2b); acc9(c3, e3, h3a, h3b);
    } else {
      for (int k = i; k < hi; ++k){
        unsigned e = bb[k];
        int s = e>>10, c = e&1023;
        float ex = __expf(lrelu(as1[s] + lad[c], 0.2f));
        acc9(c, ex, *(const float4*)(h1 + (size_t)s*D_H), *(const float4*)(h1 + (size_t)s*D_H + 4));
      }
    }
  }
  __syncthreads();
  float* outp = partial1 + (size_t)blockIdx.x*(TS*9);
  for (int r = threadIdx.x; r < TS*9; r += 512){     // SoA: [j][TS]
    int j = r / TS, loc = r - j*TS;
    outp[r] = lacc[loc*9 + j];
  }
}

// sum partials -> enc_rep -> d_out ; rep (masked->0) ; ex2 = exp(lrelu(rep·v))
__global__ void k_enc_fin(const float* __restrict__ partial1, const float* __restrict__ enc_b,
                          const float* __restrict__ e2dW, const int* __restrict__ mask_slot,
                          const float* __restrict__ v, float* __restrict__ out_rep,
                          float* __restrict__ rep, float* __restrict__ ex2){
  int i = blockIdx.x*blockDim.x + threadIdx.x;
  if (i >= N_NODES) return;
  int tau = i / TS, dloc = i - tau*TS;
  float sum[9];
#pragma unroll
  for (int j = 0; j < 9; ++j) sum[j] = 0.f;
  for (int p = 0; p < B_ENC; ++p){
    const float* pp = partial1 + ((size_t)(tau*B_ENC + p))*(TS*9) + dloc;
#pragma unroll
    for (int j = 0; j < 9; ++j) sum[j] += pp[j*TS];
  }
  float inv = 1.0f / sum[8];
  float er[D_H];
#pragma unroll
  for (int j = 0; j < D_H; ++j){
    er[j] = lrelu(sum[j]*inv + enc_b[j], 0.01f);
    out_rep[(size_t)i*D_H + j] = er[j];
  }
  bool masked = mask_slot[i] >= 0;
  float as = 0.f;
#pragma unroll
  for (int k = 0; k < D_H; ++k){
    float rv = 0.f;
#pragma unroll
    for (int j = 0; j < D_H; ++j) rv += er[j]*e2dW[k*D_H + j];
    rv = masked ? 0.f : rv;
    rep[(size_t)i*D_H + k] = rv;
    as += rv * v[k];
  }
  ex2[i] = __expf(lrelu(as, 0.2f));   // alpha_dst[masked]=0 -> weight depends only on src
}

// decoder tile aggregation in rep space (masked dst only), ILP-4
__global__ void __launch_bounds__(256) k_agg_dec(const unsigned* __restrict__ bd,
                          const int* __restrict__ gcur_dec,
                          const float* __restrict__ ex2, const float* __restrict__ rep,
                          float* __restrict__ partial2){
  __shared__ float lacc[TS*9];
  int sg = blockIdx.x / B_DEC, pb = blockIdx.x % B_DEC;
  for (int r = threadIdx.x; r < TS*9; r += 256) lacc[r] = 0.f;
  __syncthreads();
  int n  = min(gcur_dec[sg], CAPB);
  int lo = (int)(((long long)n*pb/B_DEC) & ~3LL);
  int hi = (pb == B_DEC-1) ? n : (int)(((long long)n*(pb+1)/B_DEC) & ~3LL);
  const unsigned* bb = bd + (size_t)sg*CAPB;
  auto acc9 = [&](int c, float ex, float4 ra, float4 rb){
    float* a = lacc + c*9;
    atomicAdd(a+0, ex*ra.x); atomicAdd(a+1, ex*ra.y);
    atomicAdd(a+2, ex*ra.z); atomicAdd(a+3, ex*ra.w);
    atomicAdd(a+4, ex*rb.x); atomicAdd(a+5, ex*rb.y);
    atomicAdd(a+6, ex*rb.z); atomicAdd(a+7, ex*rb.w);
    atomicAdd(a+8, ex);
  };
  for (int i = lo + 4*(int)threadIdx.x; i < hi; i += 4*256){
    if (i + 4 <= hi){
      uint4 e = *(const uint4*)(bb + i);
      int s0 = e.x>>10, c0 = e.x&1023, s1 = e.y>>10, c1 = e.y&1023;
      int s2 = e.z>>10, c2 = e.z&1023, s3 = e.w>>10, c3 = e.w&1023;
      float E0 = ex2[s0], E1 = ex2[s1], E2 = ex2[s2], E3 = ex2[s3];
      float4 r0a = *(const float4*)(rep + (size_t)s0*D_H), r0b = *(const float4*)(rep + (size_t)s0*D_H + 4);
      float4 r1a = *(const float4*)(rep + (size_t)s1*D_H), r1b = *(const float4*)(rep + (size_t)s1*D_H + 4);
      float4 r2a = *(const float4*)(rep + (size_t)s2*D_H), r2b = *(const float4*)(rep + (size_t)s2*D_H + 4);
      float4 r3a = *(const float4*)(rep + (size_t)s3*D_H), r3b = *(const float4*)(rep + (size_t)s3*D_H + 4);
      acc9(c0, E0, r0a, r0b); acc9(c1, E1, r1a, r1b);
      acc9(c2, E2, r2a, r2b); acc9(c3, E3, r3a, r3b);
    } else {
      for (int k = i; k < hi; ++k){
        unsigned e = bb[k];
        int s = e>>10, c = e&1023;
        acc9(c, ex2[s], *(const float4*)(rep + (size_t)s*D_H), *(const float4*)(rep + (size_t)s*D_H + 4));
      }
    }
  }
  __syncthreads();
  float* outp = partial2 + (size_t)blockIdx.x*(TS*9);
  for (int r = threadIdx.x; r < TS*9; r += 256){     // SoA: [j][TS]
    int j = r / TS, loc = r - j*TS;
    outp[r] = lacc[loc*9 + j];
  }
}

// loss: 640 waves over slots; last block (ticket) writes final loss
__global__ void k_loss(const float* __restrict__ partial2, const float* __restrict__ Wd,
                       const float* __restrict__ dec_b, const int* __restrict__ mask_nodes,
                       const float* __restrict__ x, float* __restrict__ cos_sum,
                       int* __restrict__ ticket, float* __restrict__ out){
  __shared__ float Ws[D_IN*D_H];
  __shared__ float wsum[4];
  for (int t = threadIdx.x; t < D_IN*D_H; t += blockDim.x) Ws[t] = Wd[t];
  __syncthreads();
  int wv = threadIdx.x >> 6, lane = threadIdx.x & 63;
  int gw = blockIdx.x*4 + wv;
  float acc = 0.f;
  for (int slot = gw; slot < N_MASK; slot += 640){
    int sg = slot / TS, sl = slot - sg*TS;
    float aj = 0.f;
    if (lane < 9){
      for (int p = 0; p < B_DEC; ++p)
        aj += partial2[((size_t)(sg*B_DEC + p))*(TS*9) + lane*TS + sl];
    }
    float a[9];
#pragma unroll
    for (int j = 0; j < 9; ++j) a[j] = __shfl(aj, j, 64);
    float inv = 1.0f / a[8];
    int node = mask_nodes[slot];
    float dot = 0.f, na = 0.f, nb = 0.f;
#pragma unroll
    for (int hh = 0; hh < 2; ++hh){
      int f = lane + 64*hh;
      float r = dec_b[f];
#pragma unroll
      for (int k = 0; k < D_H; ++k) r += a[k]*inv*Ws[f*D_H + k];
      r = lrelu(r, 0.01f);
      float xi = x[(size_t)node*D_IN + f];
      dot += r*xi; na += r*r; nb += xi*xi;
    }
    dot = wave_sum(dot); na = wave_sum(na); nb = wave_sum(nb);
    if (lane == 0) acc += dot / (fmaxf(sqrtf(na), 1e-8f)*fmaxf(sqrtf(nb), 1e-8f));
  }
  if (lane == 0) wsum[wv] = acc;
  __syncthreads();
  if (threadIdx.x == 0){
    atomicAdd(cos_sum, wsum[0]+wsum[1]+wsum[2]+wsum[3]);
    __threadfence();
    int t = atomicAdd(ticket, 1);
    if (t == gridDim.x - 1){
      float c = atomicAdd(cos_sum, 0.0f);   // atomic read-after-all
      out[0] = 1.0f - c / (float)N_MASK;
    }
  }
}

extern "C" void kernel_launch(void* const* d_in, const int* in_sizes, int n_in,
                              void* d_out, int out_size, void* d_ws, size_t ws_size,
                              hipStream_t stream){
  const float* x          = (const float*)d_in[0];
  const int*   ei         = (const int*)  d_in[1];
  const int*   mask_nodes = (const int*)  d_in[2];
  const float* token      = (const float*)d_in[3];
  const float* enc_W      = (const float*)d_in[4];
  const float* enc_as     = (const float*)d_in[5];
  const float* enc_ad     = (const float*)d_in[6];
  const float* enc_b      = (const float*)d_in[7];
  const float* e2d_W      = (const float*)d_in[8];
  const float* dec_W      = (const float*)d_in[9];
  const float* dec_as     = (const float*)d_in[10];
  const float* dec_b      = (const float*)d_in[12];
  float* out = (float*)d_out;

  char* w = (char*)d_ws;
  size_t off = 0;
  auto alloc = [&](size_t bytes)->char*{ char* p = w + off; off += (bytes + 255)/256*256; return p; };
  // ---- zero-init region ----
  int*   gcur_enc = (int*)  alloc(NTE*4);
  int*   gcur_dec = (int*)  alloc(NTD*4);
  float* cos_sum  = (float*)alloc(4);
  int*   ticket   = (int*)  alloc(4);
  size_t zero_bytes = off;
  // ---- rest ----
  int*      mask_slot = (int*)     alloc((size_t)N_NODES*4);
  unsigned* be        = (unsigned*)alloc((size_t)NTE*CAPB*4);
  unsigned* bd        = (unsigned*)alloc((size_t)NTD*CAPB*4);
  float*    h1        = (float*)   alloc((size_t)N_NODES*D_H*4);
  float*    as1       = (float*)   alloc((size_t)N_NODES*4);
  float*    ad1       = (float*)   alloc((size_t)N_NODES*4);
  float*    rep       = (float*)   alloc((size_t)N_NODES*D_H*4);
  float*    ex2       = (float*)   alloc((size_t)N_NODES*4);
  float*    partial1  = (float*)   alloc((size_t)NTE*B_ENC*TS*9*4);
  float*    partial2  = (float*)   alloc((size_t)NTD*B_DEC*TS*9*4);
  float*    vvec      = (float*)   alloc(64);

  hipMemsetAsync(d_ws, 0, zero_bytes, stream);
  hipMemsetAsync(mask_slot, 0xFF, (size_t)N_NODES*4, stream);

  k_ms      <<<(N_MASK + 255)/256, 256, 0, stream>>>(mask_nodes, mask_slot, dec_W, dec_as, vvec);
  k_pre     <<<NB_NODE + NB_BKT, 512, 0, stream>>>(x, token, enc_W, enc_as, enc_ad, mask_slot,
                                                   ei, h1, as1, ad1, gcur_enc, gcur_dec, be, bd);
  k_agg_enc <<<NTE*B_ENC, 512, 0, stream>>>(be, gcur_enc, as1, ad1, h1, partial1);
  k_enc_fin <<<(N_NODES + 255)/256, 256, 0, stream>>>(partial1, enc_b, e2d_W, mask_slot,
                                                      vvec, out + 1, rep, ex2);
  k_agg_dec <<<NTD*B_DEC, 256, 0, stream>>>(bd, gcur_dec, ex2, rep, partial2);
  k_loss    <<<160, 256, 0, stream>>>(partial2, dec_W, dec_b, mask_nodes, x, cos_sum, ticket, out);
}

// Round 6
// 207.722 us; speedup vs baseline: 5.0727x; 1.2594x over previous
//
#include <hip/hip_runtime.h>

#define N_NODES 100000
#define N_EDGES 1600000
#define N_TOT   1700000   // edges + self-loops
#define D_IN    128
#define D_H     8
#define N_MASK  10000

#define TS      896       // dst-tile size; lacc = 896*9*4 = 32256 B (+ lad 3584 B)
#define NTE     112       // ceil(N_NODES/TS)
#define NTD     12        // ceil(N_MASK/TS)
#define CAPB    17408     // per-bucket capacity (mean ~15232, sigma ~123)
#define B_ENC   9         // blocks per enc tile  -> grid 1008 (~4/CU)
#define B_DEC   24        // blocks per dec tile  -> grid 288
#define NB_NODE 196       // node blocks in k_pre (512 nodes/block, thread-per-node)
#define NB_BKT  831       // bucket blocks in k_pre (2048 edges/block)

__device__ __forceinline__ float lrelu(float v, float s){ return v > 0.f ? v : s*v; }

__device__ __forceinline__ float wave_sum(float v){
#pragma unroll
  for (int o = 32; o > 0; o >>= 1) v += __shfl_xor(v, o, 64);
  return v;
}

// mask_slot scatter + vvec (= dec_W^T dec_a_src) in block 0
__global__ void k_ms(const int* __restrict__ mask_nodes, int* __restrict__ mask_slot,
                     const float* __restrict__ Wd, const float* __restrict__ a_src,
                     float* __restrict__ vvec){
  int i = blockIdx.x*blockDim.x + threadIdx.x;
  if (i < N_MASK) mask_slot[mask_nodes[i]] = i;
  if (blockIdx.x == 0 && threadIdx.x < D_H){
    float s = 0.f;
    for (int j = 0; j < D_IN; ++j) s += a_src[j] * Wd[j*D_H + threadIdx.x];
    vvec[threadIdx.x] = s;
  }
}

// fused: blocks [0,NB_NODE)            = encoder node stage, thread-per-node
//        blocks [NB_NODE,NB_NODE+NB_BKT) = edge bucketing (2048 edges/block)
__global__ void __launch_bounds__(512) k_pre(
    const float* __restrict__ x, const float* __restrict__ token,
    const float* __restrict__ W, const float* __restrict__ a_src,
    const float* __restrict__ a_dst, const int* __restrict__ mask_slot,
    const int* __restrict__ ei,
    float* __restrict__ h1, float* __restrict__ as1, float* __restrict__ ad1,
    int* __restrict__ gcur_enc, int* __restrict__ gcur_dec,
    unsigned* __restrict__ be, unsigned* __restrict__ bd){
  __shared__ float smem[D_H*D_IN + 2*D_H];   // node: Ws+sa+sd ; bucket: histograms (aliased)
  if (blockIdx.x < NB_NODE){
    float* Ws = smem;
    float* sa = smem + D_H*D_IN;
    float* sd = sa + D_H;
    for (int t = threadIdx.x; t < D_H*D_IN; t += 512) Ws[t] = W[t];
    if (threadIdx.x < D_H)            sa[threadIdx.x] = a_src[threadIdx.x];
    else if (threadIdx.x < 2*D_H)     sd[threadIdx.x - D_H] = a_dst[threadIdx.x - D_H];
    __syncthreads();
    int wid = blockIdx.x*512 + threadIdx.x;
    if (wid >= N_NODES) return;
    const float* row = (mask_slot[wid] >= 0) ? token : (x + (size_t)wid*D_IN);
    float acc[D_H];
#pragma unroll
    for (int j = 0; j < D_H; ++j) acc[j] = 0.f;
#pragma unroll 8
    for (int i = 0; i < D_IN/4; ++i){
      float4 xc = *(const float4*)(row + 4*i);
#pragma unroll
      for (int j = 0; j < D_H; ++j){
        float4 wv = *(const float4*)(Ws + j*D_IN + 4*i);   // wave-uniform -> LDS broadcast
        acc[j] += xc.x*wv.x + xc.y*wv.y + xc.z*wv.z + xc.w*wv.w;
      }
    }
    float as = 0.f, ad = 0.f;
#pragma unroll
    for (int j = 0; j < D_H; ++j){ as += acc[j]*sa[j]; ad += acc[j]*sd[j]; }
    float4* hp = (float4*)(h1 + (size_t)wid*D_H);
    hp[0] = make_float4(acc[0], acc[1], acc[2], acc[3]);
    hp[1] = make_float4(acc[4], acc[5], acc[6], acc[7]);
    as1[wid] = as; ad1[wid] = ad;
  } else {
    int* h_enc    = (int*)smem;            // [NTE]
    int* base_enc = h_enc + NTE;           // [NTE]
    int* h_dec    = base_enc + NTE;        // [NTD]
    int* base_dec = h_dec + NTD;           // [NTD]
    int tid = threadIdx.x;
    if (tid < NTE){ h_enc[tid] = 0; }
    if (tid < NTD){ h_dec[tid] = 0; }
    __syncthreads();
    int t0 = (blockIdx.x - NB_NODE)*2048;
    int s[4], d[4], sl[4];
#pragma unroll
    for (int k = 0; k < 4; ++k){
      int t = t0 + tid + k*512;
      s[k] = -1;
      if (t < N_TOT){
        if (t < N_EDGES){ s[k] = ei[t]; d[k] = ei[N_EDGES + t]; }
        else            { s[k] = t - N_EDGES; d[k] = s[k]; }
        sl[k] = mask_slot[d[k]];
        atomicAdd(&h_enc[d[k]/TS], 1);
        if (sl[k] >= 0) atomicAdd(&h_dec[sl[k]/TS], 1);
      }
    }
    __syncthreads();
    if (tid < NTE){ base_enc[tid] = atomicAdd(&gcur_enc[tid], h_enc[tid]); h_enc[tid] = 0; }
    if (tid < NTD){ base_dec[tid] = atomicAdd(&gcur_dec[tid], h_dec[tid]); h_dec[tid] = 0; }
    __syncthreads();
#pragma unroll
    for (int k = 0; k < 4; ++k){
      if (s[k] >= 0){
        int b = d[k]/TS, loc = d[k] - b*TS;
        int idx = base_enc[b] + atomicAdd(&h_enc[b], 1);
        if (idx < CAPB) be[(size_t)b*CAPB + idx] = ((unsigned)s[k] << 10) | (unsigned)loc;
        if (sl[k] >= 0){
          int bs = sl[k]/TS, locs = sl[k] - bs*TS;
          int i2 = base_dec[bs] + atomicAdd(&h_dec[bs], 1);
          if (i2 < CAPB) bd[(size_t)bs*CAPB + i2] = ((unsigned)s[k] << 10) | (unsigned)locs;
        }
      }
    }
  }
}

// encoder tile aggregation, ILP-4: lacc[loc][0..7] += ex*h1[s], [8] += ex
__global__ void __launch_bounds__(512) k_agg_enc(const unsigned* __restrict__ be,
                          const int* __restrict__ gcur_enc,
                          const float* __restrict__ as1, const float* __restrict__ ad1,
                          const float* __restrict__ h1, float* __restrict__ partial1){
  __shared__ float lacc[TS*9];
  __shared__ float lad[TS];
  int tau = blockIdx.x / B_ENC, pb = blockIdx.x % B_ENC;
  for (int r = threadIdx.x; r < TS*9; r += 512) lacc[r] = 0.f;
  int gb = tau*TS;
  for (int r = threadIdx.x; r < TS; r += 512){
    int g = gb + r; lad[r] = (g < N_NODES) ? ad1[g] : 0.f;
  }
  __syncthreads();
  int n  = min(gcur_enc[tau], CAPB);
  int lo = (int)(((long long)n*pb/B_ENC) & ~3LL);
  int hi = (pb == B_ENC-1) ? n : (int)(((long long)n*(pb+1)/B_ENC) & ~3LL);
  const unsigned* bb = be + (size_t)tau*CAPB;
  auto acc9 = [&](int c, float ex, float4 ha, float4 hb){
    float* a = lacc + c*9;
    atomicAdd(a+0, ex*ha.x); atomicAdd(a+1, ex*ha.y);
    atomicAdd(a+2, ex*ha.z); atomicAdd(a+3, ex*ha.w);
    atomicAdd(a+4, ex*hb.x); atomicAdd(a+5, ex*hb.y);
    atomicAdd(a+6, ex*hb.z); atomicAdd(a+7, ex*hb.w);
    atomicAdd(a+8, ex);
  };
  for (int i = lo + 4*(int)threadIdx.x; i < hi; i += 4*512){
    if (i + 4 <= hi){
      uint4 e = *(const uint4*)(bb + i);
      int s0 = e.x>>10, c0 = e.x&1023, s1 = e.y>>10, c1 = e.y&1023;
      int s2 = e.z>>10, c2 = e.z&1023, s3 = e.w>>10, c3 = e.w&1023;
      float A0 = as1[s0], A1 = as1[s1], A2 = as1[s2], A3 = as1[s3];
      float4 h0a = *(const float4*)(h1 + (size_t)s0*D_H), h0b = *(const float4*)(h1 + (size_t)s0*D_H + 4);
      float4 h1a = *(const float4*)(h1 + (size_t)s1*D_H), h1b = *(const float4*)(h1 + (size_t)s1*D_H + 4);
      float4 h2a = *(const float4*)(h1 + (size_t)s2*D_H), h2b = *(const float4*)(h1 + (size_t)s2*D_H + 4);
      float4 h3a = *(const float4*)(h1 + (size_t)s3*D_H), h3b = *(const float4*)(h1 + (size_t)s3*D_H + 4);
      float e0 = __expf(lrelu(A0 + lad[c0], 0.2f));
      float e1 = __expf(lrelu(A1 + lad[c1], 0.2f));
      float e2 = __expf(lrelu(A2 + lad[c2], 0.2f));
      float e3 = __expf(lrelu(A3 + lad[c3], 0.2f));
      acc9(c0, e0, h0a, h0b); acc9(c1, e1, h1a, h1b);
      acc9(c2, e2, h2a, h2b); acc9(c3, e3, h3a, h3b);
    } else {
      for (int k = i; k < hi; ++k){
        unsigned e = bb[k];
        int s = e>>10, c = e&1023;
        float ex = __expf(lrelu(as1[s] + lad[c], 0.2f));
        acc9(c, ex, *(const float4*)(h1 + (size_t)s*D_H), *(const float4*)(h1 + (size_t)s*D_H + 4));
      }
    }
  }
  __syncthreads();
  float* outp = partial1 + (size_t)blockIdx.x*(TS*9);
  for (int r = threadIdx.x; r < TS*9; r += 512){     // SoA: [j][TS]
    int j = r / TS, loc = r - j*TS;
    outp[r] = lacc[loc*9 + j];
  }
}

// sum partials -> enc_rep -> d_out ; rep (masked->0) ; ex2 = exp(lrelu(rep·v))
__global__ void k_enc_fin(const float* __restrict__ partial1, const float* __restrict__ enc_b,
                          const float* __restrict__ e2dW, const int* __restrict__ mask_slot,
                          const float* __restrict__ v, float* __restrict__ out_rep,
                          float* __restrict__ rep, float* __restrict__ ex2){
  int i = blockIdx.x*blockDim.x + threadIdx.x;
  if (i >= N_NODES) return;
  int tau = i / TS, dloc = i - tau*TS;
  float sum[9];
#pragma unroll
  for (int j = 0; j < 9; ++j) sum[j] = 0.f;
  for (int p = 0; p < B_ENC; ++p){
    const float* pp = partial1 + ((size_t)(tau*B_ENC + p))*(TS*9) + dloc;
#pragma unroll
    for (int j = 0; j < 9; ++j) sum[j] += pp[j*TS];
  }
  float inv = 1.0f / sum[8];
  float er[D_H];
#pragma unroll
  for (int j = 0; j < D_H; ++j){
    er[j] = lrelu(sum[j]*inv + enc_b[j], 0.01f);
    out_rep[(size_t)i*D_H + j] = er[j];
  }
  bool masked = mask_slot[i] >= 0;
  float as = 0.f;
#pragma unroll
  for (int k = 0; k < D_H; ++k){
    float rv = 0.f;
#pragma unroll
    for (int j = 0; j < D_H; ++j) rv += er[j]*e2dW[k*D_H + j];
    rv = masked ? 0.f : rv;
    rep[(size_t)i*D_H + k] = rv;
    as += rv * v[k];
  }
  ex2[i] = __expf(lrelu(as, 0.2f));   // alpha_dst[masked]=0 -> weight depends only on src
}

// decoder tile aggregation in rep space (masked dst only), ILP-4
__global__ void __launch_bounds__(256) k_agg_dec(const unsigned* __restrict__ bd,
                          const int* __restrict__ gcur_dec,
                          const float* __restrict__ ex2, const float* __restrict__ rep,
                          float* __restrict__ partial2){
  __shared__ float lacc[TS*9];
  int sg = blockIdx.x / B_DEC, pb = blockIdx.x % B_DEC;
  for (int r = threadIdx.x; r < TS*9; r += 256) lacc[r] = 0.f;
  __syncthreads();
  int n  = min(gcur_dec[sg], CAPB);
  int lo = (int)(((long long)n*pb/B_DEC) & ~3LL);
  int hi = (pb == B_DEC-1) ? n : (int)(((long long)n*(pb+1)/B_DEC) & ~3LL);
  const unsigned* bb = bd + (size_t)sg*CAPB;
  auto acc9 = [&](int c, float ex, float4 ra, float4 rb){
    float* a = lacc + c*9;
    atomicAdd(a+0, ex*ra.x); atomicAdd(a+1, ex*ra.y);
    atomicAdd(a+2, ex*ra.z); atomicAdd(a+3, ex*ra.w);
    atomicAdd(a+4, ex*rb.x); atomicAdd(a+5, ex*rb.y);
    atomicAdd(a+6, ex*rb.z); atomicAdd(a+7, ex*rb.w);
    atomicAdd(a+8, ex);
  };
  for (int i = lo + 4*(int)threadIdx.x; i < hi; i += 4*256){
    if (i + 4 <= hi){
      uint4 e = *(const uint4*)(bb + i);
      int s0 = e.x>>10, c0 = e.x&1023, s1 = e.y>>10, c1 = e.y&1023;
      int s2 = e.z>>10, c2 = e.z&1023, s3 = e.w>>10, c3 = e.w&1023;
      float E0 = ex2[s0], E1 = ex2[s1], E2 = ex2[s2], E3 = ex2[s3];
      float4 r0a = *(const float4*)(rep + (size_t)s0*D_H), r0b = *(const float4*)(rep + (size_t)s0*D_H + 4);
      float4 r1a = *(const float4*)(rep + (size_t)s1*D_H), r1b = *(const float4*)(rep + (size_t)s1*D_H + 4);
      float4 r2a = *(const float4*)(rep + (size_t)s2*D_H), r2b = *(const float4*)(rep + (size_t)s2*D_H + 4);
      float4 r3a = *(const float4*)(rep + (size_t)s3*D_H), r3b = *(const float4*)(rep + (size_t)s3*D_H + 4);
      acc9(c0, E0, r0a, r0b); acc9(c1, E1, r1a, r1b);
      acc9(c2, E2, r2a, r2b); acc9(c3, E3, r3a, r3b);
    } else {
      for (int k = i; k < hi; ++k){
        unsigned e = bb[k];
        int s = e>>10, c = e&1023;
        acc9(c, ex2[s], *(const float4*)(rep + (size_t)s*D_H), *(const float4*)(rep + (size_t)s*D_H + 4));
      }
    }
  }
  __syncthreads();
  float* outp = partial2 + (size_t)blockIdx.x*(TS*9);
  for (int r = threadIdx.x; r < TS*9; r += 256){     // SoA: [j][TS]
    int j = r / TS, loc = r - j*TS;
    outp[r] = lacc[loc*9 + j];
  }
}

// loss: 640 waves over slots; last block (ticket) writes final loss
__global__ void k_loss(const float* __restrict__ partial2, const float* __restrict__ Wd,
                       const float* __restrict__ dec_b, const int* __restrict__ mask_nodes,
                       const float* __restrict__ x, float* __restrict__ cos_sum,
                       int* __restrict__ ticket, float* __restrict__ out){
  __shared__ float Ws[D_IN*D_H];
  __shared__ float wsum[4];
  for (int t = threadIdx.x; t < D_IN*D_H; t += blockDim.x) Ws[t] = Wd[t];
  __syncthreads();
  int wv = threadIdx.x >> 6, lane = threadIdx.x & 63;
  int gw = blockIdx.x*4 + wv;
  float acc = 0.f;
  for (int slot = gw; slot < N_MASK; slot += 640){
    int sg = slot / TS, sl = slot - sg*TS;
    float aj = 0.f;
    if (lane < 9){
      for (int p = 0; p < B_DEC; ++p)
        aj += partial2[((size_t)(sg*B_DEC + p))*(TS*9) + lane*TS + sl];
    }
    float a[9];
#pragma unroll
    for (int j = 0; j < 9; ++j) a[j] = __shfl(aj, j, 64);
    float inv = 1.0f / a[8];
    int node = mask_nodes[slot];
    float dot = 0.f, na = 0.f, nb = 0.f;
#pragma unroll
    for (int hh = 0; hh < 2; ++hh){
      int f = lane + 64*hh;
      float r = dec_b[f];
#pragma unroll
      for (int k = 0; k < D_H; ++k) r += a[k]*inv*Ws[f*D_H + k];
      r = lrelu(r, 0.01f);
      float xi = x[(size_t)node*D_IN + f];
      dot += r*xi; na += r*r; nb += xi*xi;
    }
    dot = wave_sum(dot); na = wave_sum(na); nb = wave_sum(nb);
    if (lane == 0) acc += dot / (fmaxf(sqrtf(na), 1e-8f)*fmaxf(sqrtf(nb), 1e-8f));
  }
  if (lane == 0) wsum[wv] = acc;
  __syncthreads();
  if (threadIdx.x == 0){
    atomicAdd(cos_sum, wsum[0]+wsum[1]+wsum[2]+wsum[3]);
    __threadfence();
    int t = atomicAdd(ticket, 1);
    if (t == gridDim.x - 1){
      float c = atomicAdd(cos_sum, 0.0f);   // atomic read-after-all
      out[0] = 1.0f - c / (float)N_MASK;
    }
  }
}

extern "C" void kernel_launch(void* const* d_in, const int* in_sizes, int n_in,
                              void* d_out, int out_size, void* d_ws, size_t ws_size,
                              hipStream_t stream){
  const float* x          = (const float*)d_in[0];
  const int*   ei         = (const int*)  d_in[1];
  const int*   mask_nodes = (const int*)  d_in[2];
  const float* token      = (const float*)d_in[3];
  const float* enc_W      = (const float*)d_in[4];
  const float* enc_as     = (const float*)d_in[5];
  const float* enc_ad     = (const float*)d_in[6];
  const float* enc_b      = (const float*)d_in[7];
  const float* e2d_W      = (const float*)d_in[8];
  const float* dec_W      = (const float*)d_in[9];
  const float* dec_as     = (const float*)d_in[10];
  const float* dec_b      = (const float*)d_in[12];
  float* out = (float*)d_out;

  char* w = (char*)d_ws;
  size_t off = 0;
  auto alloc = [&](size_t bytes)->char*{ char* p = w + off; off += (bytes + 255)/256*256; return p; };
  // ---- zero-init region ----
  int*   gcur_enc = (int*)  alloc(NTE*4);
  int*   gcur_dec = (int*)  alloc(NTD*4);
  float* cos_sum  = (float*)alloc(4);
  int*   ticket   = (int*)  alloc(4);
  size_t zero_bytes = off;
  // ---- rest ----
  int*      mask_slot = (int*)     alloc((size_t)N_NODES*4);
  unsigned* be        = (unsigned*)alloc((size_t)NTE*CAPB*4);
  unsigned* bd        = (unsigned*)alloc((size_t)NTD*CAPB*4);
  float*    h1        = (float*)   alloc((size_t)N_NODES*D_H*4);
  float*    as1       = (float*)   alloc((size_t)N_NODES*4);
  float*    ad1       = (float*)   alloc((size_t)N_NODES*4);
  float*    rep       = (float*)   alloc((size_t)N_NODES*D_H*4);
  float*    ex2       = (float*)   alloc((size_t)N_NODES*4);
  float*    partial1  = (float*)   alloc((size_t)NTE*B_ENC*TS*9*4);
  float*    partial2  = (float*)   alloc((size_t)NTD*B_DEC*TS*9*4);
  float*    vvec      = (float*)   alloc(64);

  hipMemsetAsync(d_ws, 0, zero_bytes, stream);
  hipMemsetAsync(mask_slot, 0xFF, (size_t)N_NODES*4, stream);

  k_ms      <<<(N_MASK + 255)/256, 256, 0, stream>>>(mask_nodes, mask_slot, dec_W, dec_as, vvec);
  k_pre     <<<NB_NODE + NB_BKT, 512, 0, stream>>>(x, token, enc_W, enc_as, enc_ad, mask_slot,
                                                   ei, h1, as1, ad1, gcur_enc, gcur_dec, be, bd);
  k_agg_enc <<<NTE*B_ENC, 512, 0, stream>>>(be, gcur_enc, as1, ad1, h1, partial1);
  k_enc_fin <<<(N_NODES + 255)/256, 256, 0, stream>>>(partial1, enc_b, e2d_W, mask_slot,
                                                      vvec, out + 1, rep, ex2);
  k_agg_dec <<<NTD*B_DEC, 256, 0, stream>>>(bd, gcur_dec, ex2, rep, partial2);
  k_loss    <<<160, 256, 0, stream>>>(partial2, dec_W, dec_b, mask_nodes, x, cos_sum, ticket, out);
}